// Round 1
// baseline (244.138 us; speedup 1.0000x reference)
//
#include <hip/hip_runtime.h>
#include <cmath>

#define TWO_PI_128 0.04908738521234052f  // 2*pi/128

// ---------------------------------------------------------------------------
// proj[b][c] = silu(t_emb[b]) @ temb_w[c] + temb_b[c]
// ---------------------------------------------------------------------------
__global__ __launch_bounds__(256) void proj_kernel(
    const float* __restrict__ t_emb, const float* __restrict__ temb_w,
    const float* __restrict__ temb_b, float* __restrict__ proj) {
  __shared__ float s_silu[512];
  __shared__ float s_part[64][4];
  const int b = blockIdx.x;
  const int t = threadIdx.x;
  for (int j = t; j < 512; j += 256) {
    float v = t_emb[b * 512 + j];
    s_silu[j] = v / (1.f + __expf(-v));
  }
  __syncthreads();
  const int o = t >> 2, part = t & 3;
  const float* wrow = temb_w + o * 512 + part * 128;
  const float* srow = s_silu + part * 128;
  float acc = 0.f;
#pragma unroll 8
  for (int j = 0; j < 128; ++j) acc = fmaf(srow[j], wrow[j], acc);
  s_part[o][part] = acc;
  __syncthreads();
  if (part == 0) {
    proj[b * 64 + o] =
        s_part[o][0] + s_part[o][1] + s_part[o][2] + s_part[o][3] + temb_b[o];
  }
}

// ---------------------------------------------------------------------------
// Forward truncated DFT per (b,i) plane.
// Step 1 (w axis, radix-2): X1[h][l] for l=0..15
// Step 2 (h axis, radix-2): X[k][l]  for k=0..15, scaled by 1/128 (ortho^2)
// Output layout: xfr/xfi[(b*64+i)*256 + k*16 + l]
// ---------------------------------------------------------------------------
#define XS 132  // padded stride: bank = (4*idx + off) % 32, conflict-free

__global__ __launch_bounds__(256) void fwd_dft_kernel(
    const float* __restrict__ x, float* __restrict__ xfr,
    float* __restrict__ xfi) {
  __shared__ float s_x[32 * XS];   // chunk of 32 rows
  __shared__ float s_r[16 * XS];   // X1 real, [l][h]
  __shared__ float s_i[16 * XS];   // X1 imag, [l][h]
  const int t = threadIdx.x;
  const float* xp = x + (size_t)blockIdx.x * 16384;

  const int hl = t >> 3;  // 0..31: row within chunk
  const int l0 = t & 7;   // handles modes l0 and l0+8 (same parity)
  const int l1 = l0 + 8;
  float C0, S0, C1, S1;
  sincosf(TWO_PI_128 * (float)l0, &S0, &C0);
  sincosf(TWO_PI_128 * (float)l1, &S1, &C1);
  const float p0 = (l0 & 1) ? -1.f : 1.f;  // (-1)^l

  for (int c = 0; c < 4; ++c) {
    __syncthreads();  // protect s_x (also covers nothing-before on c=0)
#pragma unroll
    for (int j = 0; j < 4; ++j) {
      int g = t + 256 * j;
      int hh = g >> 5, w4 = g & 31;
      *(float4*)(s_x + hh * XS + 4 * w4) =
          *(const float4*)(xp + (c * 32 + hh) * 128 + 4 * w4);
    }
    __syncthreads();
    const float* row = s_x + hl * XS;
    float r0 = 0.f, i0 = 0.f, r1 = 0.f, i1 = 0.f;
    float c0 = 1.f, s0 = 0.f, c1 = 1.f, s1 = 0.f;
#pragma unroll 4
    for (int w = 0; w < 64; ++w) {
      float xa = row[w], xb = row[w + 64];
      float xv = fmaf(p0, xb, xa);  // x[w] + (-1)^l x[w+64]
      r0 = fmaf(xv, c0, r0);
      i0 = fmaf(xv, -s0, i0);
      r1 = fmaf(xv, c1, r1);
      i1 = fmaf(xv, -s1, i1);
      float t0 = s0 * S0, u0 = c0 * S0;
      c0 = fmaf(c0, C0, -t0);
      s0 = fmaf(s0, C0, u0);
      float t1 = s1 * S1, u1 = c1 * S1;
      c1 = fmaf(c1, C1, -t1);
      s1 = fmaf(s1, C1, u1);
    }
    int h = c * 32 + hl;
    s_r[l0 * XS + h] = r0;
    s_i[l0 * XS + h] = i0;
    s_r[l1 * XS + h] = r1;
    s_i[l1 * XS + h] = i1;
  }
  __syncthreads();
  // step 2
  const int k = t >> 4, l = t & 15;
  const float pk = (k & 1) ? -1.f : 1.f;
  float Ck, Sk;
  sincosf(TWO_PI_128 * (float)k, &Sk, &Ck);
  const float* R = s_r + l * XS;
  const float* I = s_i + l * XS;
  float Xr = 0.f, Xi = 0.f, ch = 1.f, sh = 0.f;
#pragma unroll 4
  for (int h = 0; h < 64; ++h) {
    float ar = fmaf(pk, R[h + 64], R[h]);
    float ai = fmaf(pk, I[h + 64], I[h]);
    // (ar + i*ai) * (ch - i*sh)
    Xr = fmaf(ar, ch, Xr);
    Xr = fmaf(ai, sh, Xr);
    Xi = fmaf(ai, ch, Xi);
    Xi = fmaf(-ar, sh, Xi);
    float tt = sh * Sk, uu = ch * Sk;
    ch = fmaf(ch, Ck, -tt);
    sh = fmaf(sh, Ck, uu);
  }
  xfr[blockIdx.x * 256 + t] = Xr * 0.0078125f;
  xfi[blockIdx.x * 256 + t] = Xi * 0.0078125f;
}

// ---------------------------------------------------------------------------
// Mode mix: per mode (k,l): out[b][o] = sum_i X[b][i] * W[i][o]  (complex)
// Weights global layout [i][o][kl]; out layout [kl][b][o]
// ---------------------------------------------------------------------------
__global__ __launch_bounds__(256) void modemix_kernel(
    const float* __restrict__ xfr, const float* __restrict__ xfi,
    const float* __restrict__ wr, const float* __restrict__ wi,
    float* __restrict__ ofr, float* __restrict__ ofi) {
  __shared__ float s_xr[1024], s_xi[1024];  // [b][i]
  __shared__ float s_wr[4096], s_wi[4096];  // [i][o]
  const int kl = blockIdx.x;
  const int t = threadIdx.x;
  for (int bi = t; bi < 1024; bi += 256) {
    s_xr[bi] = xfr[bi * 256 + kl];
    s_xi[bi] = xfi[bi * 256 + kl];
  }
  for (int io = t; io < 4096; io += 256) {
    s_wr[io] = wr[io * 256 + kl];
    s_wi[io] = wi[io * 256 + kl];
  }
  __syncthreads();
  const int b0 = t >> 6;  // 0..3, b = b0 + 4j
  const int o = t & 63;
  float accr[4] = {0.f, 0.f, 0.f, 0.f};
  float acci[4] = {0.f, 0.f, 0.f, 0.f};
  for (int i = 0; i < 64; ++i) {
    float wrv = s_wr[i * 64 + o], wiv = s_wi[i * 64 + o];
#pragma unroll
    for (int j = 0; j < 4; ++j) {
      int b = b0 + 4 * j;
      float xr = s_xr[b * 64 + i], xi = s_xi[b * 64 + i];
      accr[j] = fmaf(xr, wrv, accr[j]);
      accr[j] = fmaf(-xi, wiv, accr[j]);
      acci[j] = fmaf(xr, wiv, acci[j]);
      acci[j] = fmaf(xi, wrv, acci[j]);
    }
  }
#pragma unroll
  for (int j = 0; j < 4; ++j) {
    int b = b0 + 4 * j;
    ofr[kl * 1024 + b * 64 + o] = accr[j];
    ofi[kl * 1024 + b * 64 + o] = acci[j];
  }
}

// ---------------------------------------------------------------------------
// Inverse along h: Y[b][o][h][l] = scale_l * sum_k F[k][l] e^{+2pi i k h/128}
// scale_l = (l==0 ? 1 : 2) / 128  (folds C2R doubling + ortho norm)
// ---------------------------------------------------------------------------
__global__ __launch_bounds__(256) void invh_kernel(
    const float* __restrict__ ofr, const float* __restrict__ ofi,
    float* __restrict__ Yr, float* __restrict__ Yi) {
  __shared__ float s_fr[256], s_fi[256];  // [k][l]
  __shared__ float s_c[128], s_s[128];
  const int t = threadIdx.x;
  const int plane = blockIdx.x;  // b*64 + o
  if (t < 128) {
    float sv, cv;
    sincosf(TWO_PI_128 * (float)t, &sv, &cv);
    s_c[t] = cv;
    s_s[t] = sv;
  }
  s_fr[t] = ofr[t * 1024 + plane];
  s_fi[t] = ofi[t * 1024 + plane];
  __syncthreads();
  const int l = t & 15, h0 = t >> 4;
  const float scale = (l == 0) ? 0.0078125f : 0.015625f;
#pragma unroll
  for (int j = 0; j < 8; ++j) {
    int h = h0 + 16 * j;
    float Ch = s_c[h], Sh = s_s[h];
    float yr = 0.f, yi = 0.f, ck = 1.f, sk = 0.f;
#pragma unroll
    for (int k = 0; k < 16; ++k) {
      float fr = s_fr[k * 16 + l], fi = s_fi[k * 16 + l];
      // (fr + i*fi) * (ck + i*sk)
      yr = fmaf(fr, ck, yr);
      yr = fmaf(-fi, sk, yr);
      yi = fmaf(fr, sk, yi);
      yi = fmaf(fi, ck, yi);
      float tt = sk * Sh, uu = ck * Sh;
      ck = fmaf(ck, Ch, -tt);
      sk = fmaf(sk, Ch, uu);
    }
    Yr[(size_t)plane * 2048 + h * 16 + l] = yr * scale;
    Yi[(size_t)plane * 2048 + h * 16 + l] = yi * scale;
  }
}

// ---------------------------------------------------------------------------
// Final fused: per (b,h) row:
//   spec[o][w] = sum_l Yr[o][l] cos(2pi l w/128) - Yi[o][l] sin(...)
//   byp[o][w]  = sum_i bw[o][i] x[b][i][h][w] + bb[o]
//   out = gelu(spec + byp) + proj[b][o]
// Thread: wl = t&31 -> w quad [4wl..4wl+3]; og = t>>5 -> o in [8og, 8og+8)
// ---------------------------------------------------------------------------
__global__ __launch_bounds__(256) void final_kernel(
    const float* __restrict__ x, const float* __restrict__ bw,
    const float* __restrict__ bb, const float* __restrict__ proj,
    const float* __restrict__ Yr, const float* __restrict__ Yi,
    float* __restrict__ out) {
  __shared__ float s_x[64 * 128];   // [i][w]
  __shared__ float s_bw[64 * 68];   // [i][o], padded for b128 reads
  __shared__ float s_yr[16 * 68];   // [l][o]
  __shared__ float s_yi[16 * 68];
  __shared__ float2 s_cs[128];
  __shared__ float s_pb[64];
  __shared__ float s_bias[64];
  const int h = blockIdx.x;
  const int b = blockIdx.y;
  const int t = threadIdx.x;

  if (t < 128) {
    float sv, cv;
    sincosf(TWO_PI_128 * (float)t, &sv, &cv);
    s_cs[t] = make_float2(cv, sv);
  } else if (t < 192) {
    s_pb[t - 128] = proj[b * 64 + (t - 128)];
  } else {
    s_bias[t - 192] = bb[t - 192];
  }

  const float* xb = x + (size_t)b * (64 * 16384) + h * 128;
#pragma unroll
  for (int j = 0; j < 8; ++j) {
    int g = t + 256 * j;
    int i = g >> 5, w4 = g & 31;
    *(float4*)(s_x + i * 128 + 4 * w4) =
        *(const float4*)(xb + (size_t)i * 16384 + 4 * w4);
  }
#pragma unroll
  for (int j = 0; j < 16; ++j) {
    int f = t + 256 * j;
    s_bw[(f & 63) * 68 + (f >> 6)] = bw[f];
  }
  {
    int o = t >> 2, lq = t & 3;
    size_t base = (size_t)(b * 64 + o) * 2048 + h * 16 + 4 * lq;
    float4 vr = *(const float4*)(Yr + base);
    float4 vi = *(const float4*)(Yi + base);
    s_yr[(4 * lq + 0) * 68 + o] = vr.x;
    s_yr[(4 * lq + 1) * 68 + o] = vr.y;
    s_yr[(4 * lq + 2) * 68 + o] = vr.z;
    s_yr[(4 * lq + 3) * 68 + o] = vr.w;
    s_yi[(4 * lq + 0) * 68 + o] = vi.x;
    s_yi[(4 * lq + 1) * 68 + o] = vi.y;
    s_yi[(4 * lq + 2) * 68 + o] = vi.z;
    s_yi[(4 * lq + 3) * 68 + o] = vi.w;
  }
  __syncthreads();

  const int wl = t & 31, og = t >> 5;
  float acc[8][4];
#pragma unroll
  for (int ol = 0; ol < 8; ++ol) {
    float bv = s_bias[og * 8 + ol];
    acc[ol][0] = bv;
    acc[ol][1] = bv;
    acc[ol][2] = bv;
    acc[ol][3] = bv;
  }
  // bypass 1x1 conv, register-tiled 8o x 4w
  for (int i = 0; i < 64; ++i) {
    float4 xv = *(const float4*)(s_x + i * 128 + 4 * wl);
    float4 w0 = *(const float4*)(s_bw + i * 68 + og * 8);
    float4 w1 = *(const float4*)(s_bw + i * 68 + og * 8 + 4);
    const float wv[8] = {w0.x, w0.y, w0.z, w0.w, w1.x, w1.y, w1.z, w1.w};
    const float xa[4] = {xv.x, xv.y, xv.z, xv.w};
#pragma unroll
    for (int ol = 0; ol < 8; ++ol) {
#pragma unroll
      for (int j = 0; j < 4; ++j) acc[ol][j] = fmaf(wv[ol], xa[j], acc[ol][j]);
    }
  }
  // spectral inverse along w
  const int w0i = 4 * wl;
#pragma unroll 4
  for (int l = 0; l < 16; ++l) {
    float4 r0 = *(const float4*)(s_yr + l * 68 + og * 8);
    float4 r1 = *(const float4*)(s_yr + l * 68 + og * 8 + 4);
    float4 i0 = *(const float4*)(s_yi + l * 68 + og * 8);
    float4 i1 = *(const float4*)(s_yi + l * 68 + og * 8 + 4);
    const float yrv[8] = {r0.x, r0.y, r0.z, r0.w, r1.x, r1.y, r1.z, r1.w};
    const float yiv[8] = {i0.x, i0.y, i0.z, i0.w, i1.x, i1.y, i1.z, i1.w};
    float cj[4], sj[4];
#pragma unroll
    for (int j = 0; j < 4; ++j) {
      float2 cs = s_cs[(l * (w0i + j)) & 127];
      cj[j] = cs.x;
      sj[j] = cs.y;
    }
#pragma unroll
    for (int ol = 0; ol < 8; ++ol) {
#pragma unroll
      for (int j = 0; j < 4; ++j) {
        acc[ol][j] = fmaf(yrv[ol], cj[j], acc[ol][j]);
        acc[ol][j] = fmaf(-yiv[ol], sj[j], acc[ol][j]);
      }
    }
  }
  // epilogue: exact gelu + proj
  float* op = out + ((size_t)(b * 64 + og * 8) * 128 + h) * 128 + w0i;
#pragma unroll
  for (int ol = 0; ol < 8; ++ol) {
    float pv = s_pb[og * 8 + ol];
    float4 r;
    float v;
    v = acc[ol][0];
    r.x = fmaf(0.5f * v, 1.f + erff(v * 0.70710678f), pv);
    v = acc[ol][1];
    r.y = fmaf(0.5f * v, 1.f + erff(v * 0.70710678f), pv);
    v = acc[ol][2];
    r.z = fmaf(0.5f * v, 1.f + erff(v * 0.70710678f), pv);
    v = acc[ol][3];
    r.w = fmaf(0.5f * v, 1.f + erff(v * 0.70710678f), pv);
    *(float4*)(op + (size_t)ol * 16384) = r;
  }
}

// ---------------------------------------------------------------------------
extern "C" void kernel_launch(void* const* d_in, const int* in_sizes, int n_in,
                              void* d_out, int out_size, void* d_ws,
                              size_t ws_size, hipStream_t stream) {
  (void)in_sizes;
  (void)n_in;
  (void)out_size;
  (void)ws_size;
  const float* x = (const float*)d_in[0];
  const float* t_emb = (const float*)d_in[1];
  const float* wr = (const float*)d_in[2];
  const float* wi = (const float*)d_in[3];
  const float* bw = (const float*)d_in[4];
  const float* bb = (const float*)d_in[5];
  const float* tw = (const float*)d_in[6];
  const float* tb = (const float*)d_in[7];
  float* out = (float*)d_out;

  char* ws = (char*)d_ws;
  float* Yr = (float*)(ws);                       // 8 MB
  float* Yi = (float*)(ws + ((size_t)8 << 20));   // 8 MB
  float* xfr = (float*)(ws + ((size_t)16 << 20)); // 1 MB
  float* xfi = (float*)(ws + ((size_t)17 << 20)); // 1 MB
  float* ofr = (float*)(ws + ((size_t)18 << 20)); // 1 MB
  float* ofi = (float*)(ws + ((size_t)19 << 20)); // 1 MB
  float* proj = (float*)(ws + ((size_t)20 << 20)); // 4 KB

  proj_kernel<<<16, 256, 0, stream>>>(t_emb, tw, tb, proj);
  fwd_dft_kernel<<<1024, 256, 0, stream>>>(x, xfr, xfi);
  modemix_kernel<<<256, 256, 0, stream>>>(xfr, xfi, wr, wi, ofr, ofi);
  invh_kernel<<<1024, 256, 0, stream>>>(ofr, ofi, Yr, Yi);
  final_kernel<<<dim3(128, 16), 256, 0, stream>>>(x, bw, bb, proj, Yr, Yi, out);
}

// Round 2
// 229.803 us; speedup vs baseline: 1.0624x; 1.0624x over previous
//
#include <hip/hip_runtime.h>
#include <cmath>

#define TWO_PI_128 0.04908738521234052f  // 2*pi/128

__device__ inline unsigned short f2bf(float v) {
  unsigned u = __float_as_uint(v);
  unsigned r = (u + 0x7FFFu + ((u >> 16) & 1u)) >> 16;
  return (unsigned short)r;
}
__device__ inline float bf2f(unsigned short s) {
  return __uint_as_float(((unsigned)s) << 16);
}

// ---------------------------------------------------------------------------
// proj[b][c] = silu(t_emb[b]) @ temb_w[c] + temb_b[c]
// ---------------------------------------------------------------------------
__global__ __launch_bounds__(256) void proj_kernel(
    const float* __restrict__ t_emb, const float* __restrict__ temb_w,
    const float* __restrict__ temb_b, float* __restrict__ proj) {
  __shared__ float s_silu[512];
  __shared__ float s_part[64][4];
  const int b = blockIdx.x;
  const int t = threadIdx.x;
  for (int j = t; j < 512; j += 256) {
    float v = t_emb[b * 512 + j];
    s_silu[j] = v / (1.f + __expf(-v));
  }
  __syncthreads();
  const int o = t >> 2, part = t & 3;
  const float* wrow = temb_w + o * 512 + part * 128;
  const float* srow = s_silu + part * 128;
  float acc = 0.f;
#pragma unroll 8
  for (int j = 0; j < 128; ++j) acc = fmaf(srow[j], wrow[j], acc);
  s_part[o][part] = acc;
  __syncthreads();
  if (part == 0) {
    proj[b * 64 + o] =
        s_part[o][0] + s_part[o][1] + s_part[o][2] + s_part[o][3] + temb_b[o];
  }
}

// ---------------------------------------------------------------------------
// Weight transpose: [io=4096][kl=256] -> [kl=256][io=4096], both tensors.
// ---------------------------------------------------------------------------
__global__ __launch_bounds__(256) void wtrans_kernel(
    const float* __restrict__ wr, const float* __restrict__ wi,
    float* __restrict__ wt_r, float* __restrict__ wt_i) {
  __shared__ float tile[32][33];
  const float* src = blockIdx.z ? wi : wr;
  float* dst = blockIdx.z ? wt_i : wt_r;
  const int kl0 = blockIdx.x * 32, io0 = blockIdx.y * 32;
  const int ty = threadIdx.x >> 3, tx = threadIdx.x & 7;
  float4 v = *(const float4*)(src + (size_t)(io0 + ty) * 256 + kl0 + 4 * tx);
  tile[ty][4 * tx + 0] = v.x;
  tile[ty][4 * tx + 1] = v.y;
  tile[ty][4 * tx + 2] = v.z;
  tile[ty][4 * tx + 3] = v.w;
  __syncthreads();
  float4 o;
  o.x = tile[4 * tx + 0][ty];
  o.y = tile[4 * tx + 1][ty];
  o.z = tile[4 * tx + 2][ty];
  o.w = tile[4 * tx + 3][ty];
  *(float4*)(dst + (size_t)(kl0 + ty) * 4096 + io0 + 4 * tx) = o;
}

// ---------------------------------------------------------------------------
// Forward truncated DFT per (b,i) plane. Direct global float4 reads (8 lanes
// share each address -> coalesced broadcast), LDS only for the h-transpose.
// Output layout: xf_t[kl][bi] (scatter-store; modemix reads coalesced).
// ---------------------------------------------------------------------------
__global__ __launch_bounds__(256) void fwd_dft_kernel(
    const float* __restrict__ x, float* __restrict__ xfr_t,
    float* __restrict__ xfi_t) {
  __shared__ float s_r[16 * 132];  // [l][h] padded
  __shared__ float s_i[16 * 132];
  const int t = threadIdx.x;
  const float4* xp = (const float4*)(x + (size_t)blockIdx.x * 16384);
  const int hl = t >> 3, lp = t & 7;
  const int lb = lp + 8;
  float C0, S0, C1, S1;
  sincosf(TWO_PI_128 * (float)lp, &S0, &C0);
  sincosf(TWO_PI_128 * (float)lb, &S1, &C1);
  const float p0 = (lp & 1) ? -1.f : 1.f;

#pragma unroll
  for (int c = 0; c < 4; ++c) {
    const int row = c * 32 + hl;
    const float4* rp = xp + row * 32;
    float r0 = 0.f, i0 = 0.f, r1 = 0.f, i1 = 0.f;
    float c0 = 1.f, s0 = 0.f, c1 = 1.f, s1 = 0.f;
#pragma unroll 4
    for (int wq = 0; wq < 16; ++wq) {
      float4 xa = rp[wq], xb = rp[wq + 16];
      float xs[4] = {fmaf(p0, xb.x, xa.x), fmaf(p0, xb.y, xa.y),
                     fmaf(p0, xb.z, xa.z), fmaf(p0, xb.w, xa.w)};
#pragma unroll
      for (int m = 0; m < 4; ++m) {
        float xv = xs[m];
        r0 = fmaf(xv, c0, r0);
        i0 = fmaf(xv, -s0, i0);
        r1 = fmaf(xv, c1, r1);
        i1 = fmaf(xv, -s1, i1);
        float t0 = s0 * S0, u0 = c0 * S0;
        c0 = fmaf(c0, C0, -t0);
        s0 = fmaf(s0, C0, u0);
        float t1 = s1 * S1, u1 = c1 * S1;
        c1 = fmaf(c1, C1, -t1);
        s1 = fmaf(s1, C1, u1);
      }
    }
    s_r[lp * 132 + row] = r0;
    s_i[lp * 132 + row] = i0;
    s_r[lb * 132 + row] = r1;
    s_i[lb * 132 + row] = i1;
  }
  __syncthreads();
  // step 2: h-axis DFT, radix-2 fold, b128 LDS reads
  const int k = t >> 4, l = t & 15;
  const float pk = (k & 1) ? -1.f : 1.f;
  float Ck, Sk;
  sincosf(TWO_PI_128 * (float)k, &Sk, &Ck);
  const float* R = s_r + l * 132;
  const float* I = s_i + l * 132;
  float Xr = 0.f, Xi = 0.f, ch = 1.f, sh = 0.f;
#pragma unroll 4
  for (int h4 = 0; h4 < 16; ++h4) {
    float4 Ra = *(const float4*)(R + 4 * h4);
    float4 Rb = *(const float4*)(R + 64 + 4 * h4);
    float4 Ia = *(const float4*)(I + 4 * h4);
    float4 Ib = *(const float4*)(I + 64 + 4 * h4);
    float ar[4] = {fmaf(pk, Rb.x, Ra.x), fmaf(pk, Rb.y, Ra.y),
                   fmaf(pk, Rb.z, Ra.z), fmaf(pk, Rb.w, Ra.w)};
    float ai[4] = {fmaf(pk, Ib.x, Ia.x), fmaf(pk, Ib.y, Ia.y),
                   fmaf(pk, Ib.z, Ia.z), fmaf(pk, Ib.w, Ia.w)};
#pragma unroll
    for (int m = 0; m < 4; ++m) {
      Xr = fmaf(ar[m], ch, Xr);
      Xr = fmaf(ai[m], sh, Xr);
      Xi = fmaf(ai[m], ch, Xi);
      Xi = fmaf(-ar[m], sh, Xi);
      float tt = sh * Sk, uu = ch * Sk;
      ch = fmaf(ch, Ck, -tt);
      sh = fmaf(sh, Ck, uu);
    }
  }
  xfr_t[(size_t)t * 1024 + blockIdx.x] = Xr * 0.0078125f;
  xfi_t[(size_t)t * 1024 + blockIdx.x] = Xi * 0.0078125f;
}

// ---------------------------------------------------------------------------
// Mode mix per kl: out[b][o] = sum_i X[b][i]*W[i][o] (complex).
// All loads coalesced; output scattered to [plane][kl] for invh.
// ---------------------------------------------------------------------------
__global__ __launch_bounds__(256) void modemix_kernel(
    const float* __restrict__ xfr_t, const float* __restrict__ xfi_t,
    const float* __restrict__ wt_r, const float* __restrict__ wt_i,
    float* __restrict__ ofr, float* __restrict__ ofi) {
  __shared__ float s_xr[1024], s_xi[1024];  // [b][i]
  __shared__ float s_wr[4096], s_wi[4096];  // [i][o]
  const int kl = blockIdx.x;
  const int t = threadIdx.x;
  ((float4*)s_xr)[t] = ((const float4*)(xfr_t + (size_t)kl * 1024))[t];
  ((float4*)s_xi)[t] = ((const float4*)(xfi_t + (size_t)kl * 1024))[t];
  const float4* wrp = (const float4*)(wt_r + (size_t)kl * 4096);
  const float4* wip = (const float4*)(wt_i + (size_t)kl * 4096);
#pragma unroll
  for (int j = 0; j < 4; ++j) {
    ((float4*)s_wr)[t + 256 * j] = wrp[t + 256 * j];
    ((float4*)s_wi)[t + 256 * j] = wip[t + 256 * j];
  }
  __syncthreads();
  const int b0 = t >> 6;  // b = b0 + 4j
  const int o = t & 63;
  float accr[4] = {0.f, 0.f, 0.f, 0.f};
  float acci[4] = {0.f, 0.f, 0.f, 0.f};
  for (int i = 0; i < 64; ++i) {
    float wrv = s_wr[i * 64 + o], wiv = s_wi[i * 64 + o];
#pragma unroll
    for (int j = 0; j < 4; ++j) {
      int b = b0 + 4 * j;
      float xr = s_xr[b * 64 + i], xi = s_xi[b * 64 + i];
      accr[j] = fmaf(xr, wrv, accr[j]);
      accr[j] = fmaf(-xi, wiv, accr[j]);
      acci[j] = fmaf(xr, wiv, acci[j]);
      acci[j] = fmaf(xi, wrv, acci[j]);
    }
  }
#pragma unroll
  for (int j = 0; j < 4; ++j) {
    int b = b0 + 4 * j;
    ofr[(size_t)(b * 64 + o) * 256 + kl] = accr[j];
    ofi[(size_t)(b * 64 + o) * 256 + kl] = acci[j];
  }
}

// ---------------------------------------------------------------------------
// Inverse along h. Block = (b, 16-o chunk, 16-h chunk).
// Y layout: [b][h][l][o] (l*64+o contiguous) = final_kernel's LDS layout.
// scale_l = (l==0?1:2)/128
// ---------------------------------------------------------------------------
__global__ __launch_bounds__(256) void invh_kernel(
    const float* __restrict__ ofr, const float* __restrict__ ofi,
    float* __restrict__ Yr, float* __restrict__ Yi) {
  __shared__ float s_fr[16 * 260], s_fi[16 * 260];  // [oo][k*16+l] pad 260
  __shared__ float2 s_tw[128];
  const int t = threadIdx.x;
  const int bid = blockIdx.x;
  const int b = bid >> 5, og = (bid >> 3) & 3, hg = bid & 7;
  if (t < 128) {
    float sv, cv;
    sincosf(TWO_PI_128 * (float)t, &sv, &cv);
    s_tw[t] = make_float2(cv, sv);
  }
#pragma unroll 4
  for (int pp = 0; pp < 16; ++pp) {
    s_fr[pp * 260 + t] = ofr[(size_t)(b * 64 + og * 16 + pp) * 256 + t];
    s_fi[pp * 260 + t] = ofi[(size_t)(b * 64 + og * 16 + pp) * 256 + t];
  }
  __syncthreads();
  const int ol = t & 15, hl = t >> 4;
  const int h = hg * 16 + hl;
  float yr[16], yi[16];
#pragma unroll
  for (int l = 0; l < 16; ++l) {
    yr[l] = 0.f;
    yi[l] = 0.f;
  }
  const float* FR = s_fr + ol * 260;
  const float* FI = s_fi + ol * 260;
  const float2 tw = s_tw[h];
  float ck = 1.f, sk = 0.f;
#pragma unroll 4
  for (int k = 0; k < 16; ++k) {
#pragma unroll
    for (int q = 0; q < 4; ++q) {
      float4 fr = *(const float4*)(FR + k * 16 + 4 * q);
      float4 fi = *(const float4*)(FI + k * 16 + 4 * q);
      int l = 4 * q;
      yr[l + 0] = fmaf(fr.x, ck, yr[l + 0]);
      yr[l + 0] = fmaf(-fi.x, sk, yr[l + 0]);
      yi[l + 0] = fmaf(fi.x, ck, yi[l + 0]);
      yi[l + 0] = fmaf(fr.x, sk, yi[l + 0]);
      yr[l + 1] = fmaf(fr.y, ck, yr[l + 1]);
      yr[l + 1] = fmaf(-fi.y, sk, yr[l + 1]);
      yi[l + 1] = fmaf(fi.y, ck, yi[l + 1]);
      yi[l + 1] = fmaf(fr.y, sk, yi[l + 1]);
      yr[l + 2] = fmaf(fr.z, ck, yr[l + 2]);
      yr[l + 2] = fmaf(-fi.z, sk, yr[l + 2]);
      yi[l + 2] = fmaf(fi.z, ck, yi[l + 2]);
      yi[l + 2] = fmaf(fr.z, sk, yi[l + 2]);
      yr[l + 3] = fmaf(fr.w, ck, yr[l + 3]);
      yr[l + 3] = fmaf(-fi.w, sk, yr[l + 3]);
      yi[l + 3] = fmaf(fi.w, ck, yi[l + 3]);
      yi[l + 3] = fmaf(fr.w, sk, yi[l + 3]);
    }
    float tt = sk * tw.y, uu = ck * tw.y;
    ck = fmaf(ck, tw.x, -tt);
    sk = fmaf(sk, tw.x, uu);
  }
  float* yrp = Yr + ((size_t)(b * 128 + h)) * 1024 + og * 16 + ol;
  float* yip = Yi + ((size_t)(b * 128 + h)) * 1024 + og * 16 + ol;
  yrp[0] = yr[0] * 0.0078125f;
  yip[0] = yi[0] * 0.0078125f;
#pragma unroll
  for (int l = 1; l < 16; ++l) {
    yrp[l * 64] = yr[l] * 0.015625f;
    yip[l * 64] = yi[l] * 0.015625f;
  }
}

// ---------------------------------------------------------------------------
// Final fused per (b,h): inverse-w DFT (register twiddle recurrences) +
// bypass 1x1 conv (bf16 x in LDS) + exact GELU + proj add.
// ---------------------------------------------------------------------------
__global__ __launch_bounds__(256) void final_kernel(
    const float* __restrict__ x, const float* __restrict__ bw,
    const float* __restrict__ bb, const float* __restrict__ proj,
    const float* __restrict__ Yr, const float* __restrict__ Yi,
    float* __restrict__ out) {
  __shared__ unsigned short s_xh[64 * 128];  // 16 KB, [i][w] bf16
  __shared__ float s_bw[64 * 68];            // 17.4 KB, [i][o] pad 68
  __shared__ float s_y[2048];                // [r:0/i:1024][l][o]
  __shared__ float s_pb[64];
  __shared__ float s_bias[64];
  const int h = blockIdx.x;
  const int b = blockIdx.y;
  const int t = threadIdx.x;

  if (t < 64)
    s_pb[t] = proj[b * 64 + t];
  else if (t < 128)
    s_bias[t - 64] = bb[t - 64];
  {
    const size_t ybase = ((size_t)(b * 128 + h)) * 1024;
    float4 vr = ((const float4*)(Yr + ybase))[t];
    float4 vi = ((const float4*)(Yi + ybase))[t];
    ((float4*)s_y)[t] = vr;
    ((float4*)s_y)[256 + t] = vi;
  }
  const float* xb = x + (size_t)b * 1048576 + (size_t)h * 128;
#pragma unroll
  for (int j = 0; j < 8; ++j) {
    int g = t + 256 * j;
    int i = g >> 5, w4 = g & 31;
    float4 v = *(const float4*)(xb + (size_t)i * 16384 + 4 * w4);
    ushort4 p;
    p.x = f2bf(v.x);
    p.y = f2bf(v.y);
    p.z = f2bf(v.z);
    p.w = f2bf(v.w);
    *(ushort4*)(s_xh + i * 128 + 4 * w4) = p;
  }
#pragma unroll
  for (int j = 0; j < 16; ++j) {
    int f = t + 256 * j;  // f = o*64 + i
    s_bw[(f & 63) * 68 + (f >> 6)] = bw[f];
  }
  __syncthreads();

  const int wl = t & 31, og = t >> 5;
  float acc[8][4];
#pragma unroll
  for (int ol = 0; ol < 8; ++ol) {
    float bv = s_bias[og * 8 + ol];
    acc[ol][0] = bv;
    acc[ol][1] = bv;
    acc[ol][2] = bv;
    acc[ol][3] = bv;
  }
  // bypass 1x1 conv, register-tiled 8o x 4w
  for (int i = 0; i < 64; ++i) {
    ushort4 xv = *(const ushort4*)(s_xh + i * 128 + 4 * wl);
    float xa[4] = {bf2f(xv.x), bf2f(xv.y), bf2f(xv.z), bf2f(xv.w)};
    float4 w0 = *(const float4*)(s_bw + i * 68 + og * 8);
    float4 w1 = *(const float4*)(s_bw + i * 68 + og * 8 + 4);
    const float wv[8] = {w0.x, w0.y, w0.z, w0.w, w1.x, w1.y, w1.z, w1.w};
#pragma unroll
    for (int ol = 0; ol < 8; ++ol) {
#pragma unroll
      for (int j = 0; j < 4; ++j) acc[ol][j] = fmaf(wv[ol], xa[j], acc[ol][j]);
    }
  }
  // spectral inverse along w: register twiddle recurrences (no LDS scatter)
  float cw[4], sw[4], cj[4], sj[4];
#pragma unroll
  for (int j = 0; j < 4; ++j) {
    sincosf(TWO_PI_128 * (float)(4 * wl + j), &sw[j], &cw[j]);
    cj[j] = 1.f;
    sj[j] = 0.f;
  }
#pragma unroll 4
  for (int l = 0; l < 16; ++l) {
    float4 r0 = *(const float4*)(s_y + l * 64 + og * 8);
    float4 r1 = *(const float4*)(s_y + l * 64 + og * 8 + 4);
    float4 i0 = *(const float4*)(s_y + 1024 + l * 64 + og * 8);
    float4 i1 = *(const float4*)(s_y + 1024 + l * 64 + og * 8 + 4);
    const float yrv[8] = {r0.x, r0.y, r0.z, r0.w, r1.x, r1.y, r1.z, r1.w};
    const float yiv[8] = {i0.x, i0.y, i0.z, i0.w, i1.x, i1.y, i1.z, i1.w};
#pragma unroll
    for (int ol = 0; ol < 8; ++ol) {
#pragma unroll
      for (int j = 0; j < 4; ++j) {
        acc[ol][j] = fmaf(yrv[ol], cj[j], acc[ol][j]);
        acc[ol][j] = fmaf(-yiv[ol], sj[j], acc[ol][j]);
      }
    }
#pragma unroll
    for (int j = 0; j < 4; ++j) {
      float tt = sj[j] * sw[j], uu = cj[j] * sw[j];
      cj[j] = fmaf(cj[j], cw[j], -tt);
      sj[j] = fmaf(sj[j], cw[j], uu);
    }
  }
  // epilogue: exact gelu + proj
  const int w0i = 4 * wl;
  float* op = out + ((size_t)(b * 64 + og * 8) * 128 + h) * 128 + w0i;
#pragma unroll
  for (int ol = 0; ol < 8; ++ol) {
    float pv = s_pb[og * 8 + ol];
    float4 r;
    float v;
    v = acc[ol][0];
    r.x = fmaf(0.5f * v, 1.f + erff(v * 0.70710678f), pv);
    v = acc[ol][1];
    r.y = fmaf(0.5f * v, 1.f + erff(v * 0.70710678f), pv);
    v = acc[ol][2];
    r.z = fmaf(0.5f * v, 1.f + erff(v * 0.70710678f), pv);
    v = acc[ol][3];
    r.w = fmaf(0.5f * v, 1.f + erff(v * 0.70710678f), pv);
    *(float4*)(op + (size_t)ol * 16384) = r;
  }
}

// ---------------------------------------------------------------------------
extern "C" void kernel_launch(void* const* d_in, const int* in_sizes, int n_in,
                              void* d_out, int out_size, void* d_ws,
                              size_t ws_size, hipStream_t stream) {
  (void)in_sizes;
  (void)n_in;
  (void)out_size;
  (void)ws_size;
  const float* x = (const float*)d_in[0];
  const float* t_emb = (const float*)d_in[1];
  const float* wr = (const float*)d_in[2];
  const float* wi = (const float*)d_in[3];
  const float* bw = (const float*)d_in[4];
  const float* bb = (const float*)d_in[5];
  const float* tw = (const float*)d_in[6];
  const float* tb = (const float*)d_in[7];
  float* out = (float*)d_out;

  char* ws = (char*)d_ws;
  // Liveness-based aliasing (peak 19 MB):
  //   proj @0; ofr @1M; ofi @2M;
  //   xfr_t @3M, xfi_t @4M, wt_r @5M..9M, wt_i @9M..13M  (dead after modemix)
  //   Yr @3M..11M, Yi @11M..19M                          (written by invh after)
  float* proj = (float*)(ws);
  float* ofr = (float*)(ws + ((size_t)1 << 20));
  float* ofi = (float*)(ws + ((size_t)2 << 20));
  float* xfr_t = (float*)(ws + ((size_t)3 << 20));
  float* xfi_t = (float*)(ws + ((size_t)4 << 20));
  float* wt_r = (float*)(ws + ((size_t)5 << 20));
  float* wt_i = (float*)(ws + ((size_t)9 << 20));
  float* Yr = (float*)(ws + ((size_t)3 << 20));
  float* Yi = (float*)(ws + ((size_t)11 << 20));

  proj_kernel<<<16, 256, 0, stream>>>(t_emb, tw, tb, proj);
  wtrans_kernel<<<dim3(8, 128, 2), 256, 0, stream>>>(wr, wi, wt_r, wt_i);
  fwd_dft_kernel<<<1024, 256, 0, stream>>>(x, xfr_t, xfi_t);
  modemix_kernel<<<256, 256, 0, stream>>>(xfr_t, xfi_t, wt_r, wt_i, ofr, ofi);
  invh_kernel<<<512, 256, 0, stream>>>(ofr, ofi, Yr, Yi);
  final_kernel<<<dim3(128, 16), 256, 0, stream>>>(x, bw, bb, proj, Yr, Yi, out);
}

// Round 3
// 201.380 us; speedup vs baseline: 1.2123x; 1.1411x over previous
//
#include <hip/hip_runtime.h>
#include <cmath>

#define TWO_PI_128 0.04908738521234052f  // 2*pi/128

typedef __attribute__((ext_vector_type(8))) short bf16x8;
typedef __attribute__((ext_vector_type(4))) float f32x4;

__device__ inline unsigned short f2bf(float v) {
  unsigned u = __float_as_uint(v);
  unsigned r = (u + 0x7FFFu + ((u >> 16) & 1u)) >> 16;
  return (unsigned short)r;
}

// ---------------------------------------------------------------------------
// proj[b][c] = silu(t_emb[b]) @ temb_w[c] + temb_b[c]
// ---------------------------------------------------------------------------
__global__ __launch_bounds__(256) void proj_kernel(
    const float* __restrict__ t_emb, const float* __restrict__ temb_w,
    const float* __restrict__ temb_b, float* __restrict__ proj) {
  __shared__ float s_silu[512];
  __shared__ float s_part[64][4];
  const int b = blockIdx.x;
  const int t = threadIdx.x;
  for (int j = t; j < 512; j += 256) {
    float v = t_emb[b * 512 + j];
    s_silu[j] = v / (1.f + __expf(-v));
  }
  __syncthreads();
  const int o = t >> 2, part = t & 3;
  const float* wrow = temb_w + o * 512 + part * 128;
  const float* srow = s_silu + part * 128;
  float acc = 0.f;
#pragma unroll 8
  for (int j = 0; j < 128; ++j) acc = fmaf(srow[j], wrow[j], acc);
  s_part[o][part] = acc;
  __syncthreads();
  if (part == 0) {
    proj[b * 64 + o] =
        s_part[o][0] + s_part[o][1] + s_part[o][2] + s_part[o][3] + temb_b[o];
  }
}

// ---------------------------------------------------------------------------
// Weight transpose: [io=4096][kl=256] -> [kl=256][io=4096], both tensors.
// ---------------------------------------------------------------------------
__global__ __launch_bounds__(256) void wtrans_kernel(
    const float* __restrict__ wr, const float* __restrict__ wi,
    float* __restrict__ wt_r, float* __restrict__ wt_i) {
  __shared__ float tile[32][33];
  const float* src = blockIdx.z ? wi : wr;
  float* dst = blockIdx.z ? wt_i : wt_r;
  const int kl0 = blockIdx.x * 32, io0 = blockIdx.y * 32;
  const int ty = threadIdx.x >> 3, tx = threadIdx.x & 7;
  float4 v = *(const float4*)(src + (size_t)(io0 + ty) * 256 + kl0 + 4 * tx);
  tile[ty][4 * tx + 0] = v.x;
  tile[ty][4 * tx + 1] = v.y;
  tile[ty][4 * tx + 2] = v.z;
  tile[ty][4 * tx + 3] = v.w;
  __syncthreads();
  float4 o;
  o.x = tile[4 * tx + 0][ty];
  o.y = tile[4 * tx + 1][ty];
  o.z = tile[4 * tx + 2][ty];
  o.w = tile[4 * tx + 3][ty];
  *(float4*)(dst + (size_t)(kl0 + ty) * 4096 + io0 + 4 * tx) = o;
}

// ---------------------------------------------------------------------------
// Forward truncated DFT per (b,i) plane (unchanged from R2).
// ---------------------------------------------------------------------------
__global__ __launch_bounds__(256) void fwd_dft_kernel(
    const float* __restrict__ x, float* __restrict__ xfr_t,
    float* __restrict__ xfi_t) {
  __shared__ float s_r[16 * 132];  // [l][h] padded
  __shared__ float s_i[16 * 132];
  const int t = threadIdx.x;
  const float4* xp = (const float4*)(x + (size_t)blockIdx.x * 16384);
  const int hl = t >> 3, lp = t & 7;
  const int lb = lp + 8;
  float C0, S0, C1, S1;
  sincosf(TWO_PI_128 * (float)lp, &S0, &C0);
  sincosf(TWO_PI_128 * (float)lb, &S1, &C1);
  const float p0 = (lp & 1) ? -1.f : 1.f;

#pragma unroll
  for (int c = 0; c < 4; ++c) {
    const int row = c * 32 + hl;
    const float4* rp = xp + row * 32;
    float r0 = 0.f, i0 = 0.f, r1 = 0.f, i1 = 0.f;
    float c0 = 1.f, s0 = 0.f, c1 = 1.f, s1 = 0.f;
#pragma unroll 4
    for (int wq = 0; wq < 16; ++wq) {
      float4 xa = rp[wq], xb = rp[wq + 16];
      float xs[4] = {fmaf(p0, xb.x, xa.x), fmaf(p0, xb.y, xa.y),
                     fmaf(p0, xb.z, xa.z), fmaf(p0, xb.w, xa.w)};
#pragma unroll
      for (int m = 0; m < 4; ++m) {
        float xv = xs[m];
        r0 = fmaf(xv, c0, r0);
        i0 = fmaf(xv, -s0, i0);
        r1 = fmaf(xv, c1, r1);
        i1 = fmaf(xv, -s1, i1);
        float t0 = s0 * S0, u0 = c0 * S0;
        c0 = fmaf(c0, C0, -t0);
        s0 = fmaf(s0, C0, u0);
        float t1 = s1 * S1, u1 = c1 * S1;
        c1 = fmaf(c1, C1, -t1);
        s1 = fmaf(s1, C1, u1);
      }
    }
    s_r[lp * 132 + row] = r0;
    s_i[lp * 132 + row] = i0;
    s_r[lb * 132 + row] = r1;
    s_i[lb * 132 + row] = i1;
  }
  __syncthreads();
  const int k = t >> 4, l = t & 15;
  const float pk = (k & 1) ? -1.f : 1.f;
  float Ck, Sk;
  sincosf(TWO_PI_128 * (float)k, &Sk, &Ck);
  const float* R = s_r + l * 132;
  const float* I = s_i + l * 132;
  float Xr = 0.f, Xi = 0.f, ch = 1.f, sh = 0.f;
#pragma unroll 4
  for (int h4 = 0; h4 < 16; ++h4) {
    float4 Ra = *(const float4*)(R + 4 * h4);
    float4 Rb = *(const float4*)(R + 64 + 4 * h4);
    float4 Ia = *(const float4*)(I + 4 * h4);
    float4 Ib = *(const float4*)(I + 64 + 4 * h4);
    float ar[4] = {fmaf(pk, Rb.x, Ra.x), fmaf(pk, Rb.y, Ra.y),
                   fmaf(pk, Rb.z, Ra.z), fmaf(pk, Rb.w, Ra.w)};
    float ai[4] = {fmaf(pk, Ib.x, Ia.x), fmaf(pk, Ib.y, Ia.y),
                   fmaf(pk, Ib.z, Ia.z), fmaf(pk, Ib.w, Ia.w)};
#pragma unroll
    for (int m = 0; m < 4; ++m) {
      Xr = fmaf(ar[m], ch, Xr);
      Xr = fmaf(ai[m], sh, Xr);
      Xi = fmaf(ai[m], ch, Xi);
      Xi = fmaf(-ar[m], sh, Xi);
      float tt = sh * Sk, uu = ch * Sk;
      ch = fmaf(ch, Ck, -tt);
      sh = fmaf(sh, Ck, uu);
    }
  }
  xfr_t[(size_t)t * 1024 + blockIdx.x] = Xr * 0.0078125f;
  xfi_t[(size_t)t * 1024 + blockIdx.x] = Xi * 0.0078125f;
}

// ---------------------------------------------------------------------------
// Mode mix per kl (unchanged from R2).
// ---------------------------------------------------------------------------
__global__ __launch_bounds__(256) void modemix_kernel(
    const float* __restrict__ xfr_t, const float* __restrict__ xfi_t,
    const float* __restrict__ wt_r, const float* __restrict__ wt_i,
    float* __restrict__ ofr, float* __restrict__ ofi) {
  __shared__ float s_xr[1024], s_xi[1024];  // [b][i]
  __shared__ float s_wr[4096], s_wi[4096];  // [i][o]
  const int kl = blockIdx.x;
  const int t = threadIdx.x;
  ((float4*)s_xr)[t] = ((const float4*)(xfr_t + (size_t)kl * 1024))[t];
  ((float4*)s_xi)[t] = ((const float4*)(xfi_t + (size_t)kl * 1024))[t];
  const float4* wrp = (const float4*)(wt_r + (size_t)kl * 4096);
  const float4* wip = (const float4*)(wt_i + (size_t)kl * 4096);
#pragma unroll
  for (int j = 0; j < 4; ++j) {
    ((float4*)s_wr)[t + 256 * j] = wrp[t + 256 * j];
    ((float4*)s_wi)[t + 256 * j] = wip[t + 256 * j];
  }
  __syncthreads();
  const int b0 = t >> 6;
  const int o = t & 63;
  float accr[4] = {0.f, 0.f, 0.f, 0.f};
  float acci[4] = {0.f, 0.f, 0.f, 0.f};
  for (int i = 0; i < 64; ++i) {
    float wrv = s_wr[i * 64 + o], wiv = s_wi[i * 64 + o];
#pragma unroll
    for (int j = 0; j < 4; ++j) {
      int b = b0 + 4 * j;
      float xr = s_xr[b * 64 + i], xi = s_xi[b * 64 + i];
      accr[j] = fmaf(xr, wrv, accr[j]);
      accr[j] = fmaf(-xi, wiv, accr[j]);
      acci[j] = fmaf(xr, wiv, acci[j]);
      acci[j] = fmaf(xi, wrv, acci[j]);
    }
  }
#pragma unroll
  for (int j = 0; j < 4; ++j) {
    int b = b0 + 4 * j;
    ofr[(size_t)(b * 64 + o) * 256 + kl] = accr[j];
    ofi[(size_t)(b * 64 + o) * 256 + kl] = acci[j];
  }
}

// ---------------------------------------------------------------------------
// Inverse along h. Output: packed bf16 Y[b][h][o][kk], kk=0..15 Yr, 16..31 Yi
// (64 B per (b,h,o) row) — exactly final_kernel's A-fragment staging layout.
// ---------------------------------------------------------------------------
__global__ __launch_bounds__(256) void invh_kernel(
    const float* __restrict__ ofr, const float* __restrict__ ofi,
    uint4* __restrict__ Ybf) {
  __shared__ float s_fr[16 * 260], s_fi[16 * 260];
  __shared__ float2 s_tw[128];
  const int t = threadIdx.x;
  const int bid = blockIdx.x;
  const int b = bid >> 5, og = (bid >> 3) & 3, hg = bid & 7;
  if (t < 128) {
    float sv, cv;
    sincosf(TWO_PI_128 * (float)t, &sv, &cv);
    s_tw[t] = make_float2(cv, sv);
  }
#pragma unroll 4
  for (int pp = 0; pp < 16; ++pp) {
    s_fr[pp * 260 + t] = ofr[(size_t)(b * 64 + og * 16 + pp) * 256 + t];
    s_fi[pp * 260 + t] = ofi[(size_t)(b * 64 + og * 16 + pp) * 256 + t];
  }
  __syncthreads();
  const int ol = t & 15, hl = t >> 4;
  const int h = hg * 16 + hl;
  float yr[16], yi[16];
#pragma unroll
  for (int l = 0; l < 16; ++l) {
    yr[l] = 0.f;
    yi[l] = 0.f;
  }
  const float* FR = s_fr + ol * 260;
  const float* FI = s_fi + ol * 260;
  const float2 tw = s_tw[h];
  float ck = 1.f, sk = 0.f;
#pragma unroll 4
  for (int k = 0; k < 16; ++k) {
#pragma unroll
    for (int q = 0; q < 4; ++q) {
      float4 fr = *(const float4*)(FR + k * 16 + 4 * q);
      float4 fi = *(const float4*)(FI + k * 16 + 4 * q);
      int l = 4 * q;
      yr[l + 0] = fmaf(fr.x, ck, yr[l + 0]);
      yr[l + 0] = fmaf(-fi.x, sk, yr[l + 0]);
      yi[l + 0] = fmaf(fi.x, ck, yi[l + 0]);
      yi[l + 0] = fmaf(fr.x, sk, yi[l + 0]);
      yr[l + 1] = fmaf(fr.y, ck, yr[l + 1]);
      yr[l + 1] = fmaf(-fi.y, sk, yr[l + 1]);
      yi[l + 1] = fmaf(fi.y, ck, yi[l + 1]);
      yi[l + 1] = fmaf(fr.y, sk, yi[l + 1]);
      yr[l + 2] = fmaf(fr.z, ck, yr[l + 2]);
      yr[l + 2] = fmaf(-fi.z, sk, yr[l + 2]);
      yi[l + 2] = fmaf(fi.z, ck, yi[l + 2]);
      yi[l + 2] = fmaf(fr.z, sk, yi[l + 2]);
      yr[l + 3] = fmaf(fr.w, ck, yr[l + 3]);
      yr[l + 3] = fmaf(-fi.w, sk, yr[l + 3]);
      yi[l + 3] = fmaf(fi.w, ck, yi[l + 3]);
      yi[l + 3] = fmaf(fr.w, sk, yi[l + 3]);
    }
    float tt = sk * tw.y, uu = ck * tw.y;
    ck = fmaf(ck, tw.x, -tt);
    sk = fmaf(sk, tw.x, uu);
  }
  // pack to bf16 with C2R scale folded in
  unsigned int u[16];
  {
    float sc[16];
    sc[0] = 0.0078125f;
#pragma unroll
    for (int l = 1; l < 16; ++l) sc[l] = 0.015625f;
#pragma unroll
    for (int j = 0; j < 8; ++j) {
      u[j] = (unsigned)f2bf(yr[2 * j] * sc[2 * j]) |
             ((unsigned)f2bf(yr[2 * j + 1] * sc[2 * j + 1]) << 16);
      u[8 + j] = (unsigned)f2bf(yi[2 * j] * sc[2 * j]) |
                 ((unsigned)f2bf(yi[2 * j + 1] * sc[2 * j + 1]) << 16);
    }
  }
  uint4* dst = Ybf + ((size_t)(b * 128 + h) * 64 + og * 16 + ol) * 4;
  dst[0] = make_uint4(u[0], u[1], u[2], u[3]);
  dst[1] = make_uint4(u[4], u[5], u[6], u[7]);
  dst[2] = make_uint4(u[8], u[9], u[10], u[11]);
  dst[3] = make_uint4(u[12], u[13], u[14], u[15]);
}

// ---------------------------------------------------------------------------
// Final fused, MFMA: per (b,h):
//   OUT[o=64][w=128] = A[o][k=96] @ B[k=96][w], where
//     A = [ bw (k=0..63) | Yr (64..79) | Yi (80..95) ]  (bf16, LDS, k-inner)
//     B = [ x[b][k][h][w] | cos(2pi l w/128) | -sin(2pi l w/128) ]
//   acc init = bb[o]; epilogue: gelu + proj.
// Wave wv owns w-strip [32wv, 32wv+32) x all o. 16x16x32 bf16 MFMA.
// ---------------------------------------------------------------------------
__global__ __launch_bounds__(256) void final_kernel(
    const float* __restrict__ x, const float* __restrict__ bw,
    const float* __restrict__ bb, const float* __restrict__ proj,
    const uint4* __restrict__ Ybf, float* __restrict__ out) {
#define AR 104  // s_A row stride (elems): 16B-aligned rows, conflict-spread
  __shared__ unsigned short s_A[64 * AR];
  __shared__ float s_bb[64];
  __shared__ float s_pb[64];
  const int h = blockIdx.x, b = blockIdx.y, t = threadIdx.x;

  if (t < 64)
    s_bb[t] = bb[t];
  else if (t < 128)
    s_pb[t - 64] = proj[b * 64 + (t - 64)];

  {  // stage bw -> s_A[o][0..63] (bf16)
    const int o = t >> 2, q = t & 3;
    const float4* src = (const float4*)(bw + o * 64 + q * 16);
    unsigned int u[8];
#pragma unroll
    for (int m = 0; m < 4; ++m) {
      float4 v = src[m];
      u[2 * m] = (unsigned)f2bf(v.x) | ((unsigned)f2bf(v.y) << 16);
      u[2 * m + 1] = (unsigned)f2bf(v.z) | ((unsigned)f2bf(v.w) << 16);
    }
    uint4* dst = (uint4*)(s_A + o * AR + q * 16);
    dst[0] = make_uint4(u[0], u[1], u[2], u[3]);
    dst[1] = make_uint4(u[4], u[5], u[6], u[7]);
  }
  {  // stage Y -> s_A[o][64..95]
    const int o = t >> 2, q = t & 3;
    uint4 v = Ybf[((size_t)(b * 128 + h) * 64 + o) * 4 + q];
    *(uint4*)(s_A + o * AR + 64 + q * 8) = v;
  }
  __syncthreads();

  const int wv = t >> 6, lane = t & 63;
  const int l15 = lane & 15, quad = lane >> 4;
  const int n0w = wv * 32;

  f32x4 acc[4][2];
#pragma unroll
  for (int mt = 0; mt < 4; ++mt) {
    f32x4 bv = *(const f32x4*)(s_bb + mt * 16 + quad * 4);
    acc[mt][0] = bv;
    acc[mt][1] = bv;
  }

  // x part: K = 0..63 (two k-steps), B-frags straight from global (fp32->bf16)
  const float* xrow = x + (size_t)b * 1048576 + (size_t)h * 128 + n0w + l15;
#pragma unroll
  for (int ks = 0; ks < 64; ks += 32) {
    union {
      bf16x8 v;
      unsigned short u[8];
    } bx[2];
#pragma unroll
    for (int nt = 0; nt < 2; ++nt) {
      float xv[8];
#pragma unroll
      for (int j = 0; j < 8; ++j)
        xv[j] = xrow[(size_t)(ks + quad * 8 + j) * 16384 + nt * 16];
#pragma unroll
      for (int j = 0; j < 8; ++j) bx[nt].u[j] = f2bf(xv[j]);
    }
#pragma unroll
    for (int mt = 0; mt < 4; ++mt) {
      bf16x8 a =
          *(const bf16x8*)(s_A + (mt * 16 + l15) * AR + ks + quad * 8);
      acc[mt][0] = __builtin_amdgcn_mfma_f32_16x16x32_bf16(a, bx[0].v,
                                                           acc[mt][0], 0, 0, 0);
      acc[mt][1] = __builtin_amdgcn_mfma_f32_16x16x32_bf16(a, bx[1].v,
                                                           acc[mt][1], 0, 0, 0);
    }
  }

  // spectral part: K = 64..95; B rows are cos(l*w) (kk<16) / -sin (kk>=16)
  {
    const int lbase = (quad & 1) * 8;  // l of j=0
    const bool iscos = (quad < 2);
    union {
      bf16x8 v;
      unsigned short u[8];
    } bs[2];
#pragma unroll
    for (int nt = 0; nt < 2; ++nt) {
      const int wn = n0w + nt * 16 + l15;
      float st, ct, ss, cc;
      sincosf(TWO_PI_128 * (float)wn, &st, &ct);
      sincosf(TWO_PI_128 * (float)(wn * lbase), &ss, &cc);
#pragma unroll
      for (int j = 0; j < 8; ++j) {
        bs[nt].u[j] = f2bf(iscos ? cc : -ss);
        float nc = cc * ct - ss * st;
        ss = ss * ct + cc * st;
        cc = nc;
      }
    }
#pragma unroll
    for (int mt = 0; mt < 4; ++mt) {
      bf16x8 a = *(const bf16x8*)(s_A + (mt * 16 + l15) * AR + 64 + quad * 8);
      acc[mt][0] = __builtin_amdgcn_mfma_f32_16x16x32_bf16(a, bs[0].v,
                                                           acc[mt][0], 0, 0, 0);
      acc[mt][1] = __builtin_amdgcn_mfma_f32_16x16x32_bf16(a, bs[1].v,
                                                           acc[mt][1], 0, 0, 0);
    }
  }

  // epilogue: gelu + proj, store (D layout: n=lane&15 -> w, m=quad*4+r -> o)
#pragma unroll
  for (int mt = 0; mt < 4; ++mt) {
    f32x4 pv = *(const f32x4*)(s_pb + mt * 16 + quad * 4);
#pragma unroll
    for (int nt = 0; nt < 2; ++nt) {
      const int wcol = n0w + nt * 16 + l15;
#pragma unroll
      for (int r = 0; r < 4; ++r) {
        const int o = mt * 16 + quad * 4 + r;
        float v = acc[mt][nt][r];
        float g = fmaf(0.5f * v, 1.f + erff(v * 0.70710678f), pv[r]);
        out[((size_t)(b * 64 + o) * 128 + h) * 128 + wcol] = g;
      }
    }
  }
#undef AR
}

// ---------------------------------------------------------------------------
extern "C" void kernel_launch(void* const* d_in, const int* in_sizes, int n_in,
                              void* d_out, int out_size, void* d_ws,
                              size_t ws_size, hipStream_t stream) {
  (void)in_sizes;
  (void)n_in;
  (void)out_size;
  (void)ws_size;
  const float* x = (const float*)d_in[0];
  const float* t_emb = (const float*)d_in[1];
  const float* wr = (const float*)d_in[2];
  const float* wi = (const float*)d_in[3];
  const float* bw = (const float*)d_in[4];
  const float* bb = (const float*)d_in[5];
  const float* tw = (const float*)d_in[6];
  const float* tb = (const float*)d_in[7];
  float* out = (float*)d_out;

  char* ws = (char*)d_ws;
  // proj@0; ofr@1M; ofi@2M; xfr_t@3M, xfi_t@4M, wt_r@5M..9M, wt_i@9M..13M
  // (dead after modemix); Ybf@3M..11M (bf16, written by invh afterwards)
  float* proj = (float*)(ws);
  float* ofr = (float*)(ws + ((size_t)1 << 20));
  float* ofi = (float*)(ws + ((size_t)2 << 20));
  float* xfr_t = (float*)(ws + ((size_t)3 << 20));
  float* xfi_t = (float*)(ws + ((size_t)4 << 20));
  float* wt_r = (float*)(ws + ((size_t)5 << 20));
  float* wt_i = (float*)(ws + ((size_t)9 << 20));
  uint4* Ybf = (uint4*)(ws + ((size_t)3 << 20));

  proj_kernel<<<16, 256, 0, stream>>>(t_emb, tw, tb, proj);
  wtrans_kernel<<<dim3(8, 128, 2), 256, 0, stream>>>(wr, wi, wt_r, wt_i);
  fwd_dft_kernel<<<1024, 256, 0, stream>>>(x, xfr_t, xfi_t);
  modemix_kernel<<<256, 256, 0, stream>>>(xfr_t, xfi_t, wt_r, wt_i, ofr, ofi);
  invh_kernel<<<512, 256, 0, stream>>>(ofr, ofi, Ybf);
  final_kernel<<<dim3(128, 16), 256, 0, stream>>>(x, bw, bb, proj, Ybf, out);
}

// Round 4
// 184.621 us; speedup vs baseline: 1.3224x; 1.0908x over previous
//
#include <hip/hip_runtime.h>
#include <cmath>

#define TWO_PI_128 0.04908738521234052f  // 2*pi/128

typedef __attribute__((ext_vector_type(8))) short bf16x8;
typedef __attribute__((ext_vector_type(4))) float f32x4;

__device__ inline unsigned short f2bf(float v) {
  unsigned u = __float_as_uint(v);
  unsigned r = (u + 0x7FFFu + ((u >> 16) & 1u)) >> 16;
  return (unsigned short)r;
}

// ---------------------------------------------------------------------------
// proj[b][c] = silu(t_emb[b]) @ temb_w[c] + temb_b[c]
// ---------------------------------------------------------------------------
__global__ __launch_bounds__(256) void proj_kernel(
    const float* __restrict__ t_emb, const float* __restrict__ temb_w,
    const float* __restrict__ temb_b, float* __restrict__ proj) {
  __shared__ float s_silu[512];
  __shared__ float s_part[64][4];
  const int b = blockIdx.x;
  const int t = threadIdx.x;
  for (int j = t; j < 512; j += 256) {
    float v = t_emb[b * 512 + j];
    s_silu[j] = v / (1.f + __expf(-v));
  }
  __syncthreads();
  const int o = t >> 2, part = t & 3;
  const float* wrow = temb_w + o * 512 + part * 128;
  const float* srow = s_silu + part * 128;
  float acc = 0.f;
#pragma unroll 8
  for (int j = 0; j < 128; ++j) acc = fmaf(srow[j], wrow[j], acc);
  s_part[o][part] = acc;
  __syncthreads();
  if (part == 0) {
    proj[b * 64 + o] =
        s_part[o][0] + s_part[o][1] + s_part[o][2] + s_part[o][3] + temb_b[o];
  }
}

// ---------------------------------------------------------------------------
// Weight transpose: [io=4096][kl=256] -> [kl=256][io=4096], both tensors.
// ---------------------------------------------------------------------------
__global__ __launch_bounds__(256) void wtrans_kernel(
    const float* __restrict__ wr, const float* __restrict__ wi,
    float* __restrict__ wt_r, float* __restrict__ wt_i) {
  __shared__ float tile[32][33];
  const float* src = blockIdx.z ? wi : wr;
  float* dst = blockIdx.z ? wt_i : wt_r;
  const int kl0 = blockIdx.x * 32, io0 = blockIdx.y * 32;
  const int ty = threadIdx.x >> 3, tx = threadIdx.x & 7;
  float4 v = *(const float4*)(src + (size_t)(io0 + ty) * 256 + kl0 + 4 * tx);
  tile[ty][4 * tx + 0] = v.x;
  tile[ty][4 * tx + 1] = v.y;
  tile[ty][4 * tx + 2] = v.z;
  tile[ty][4 * tx + 3] = v.w;
  __syncthreads();
  float4 o;
  o.x = tile[4 * tx + 0][ty];
  o.y = tile[4 * tx + 1][ty];
  o.z = tile[4 * tx + 2][ty];
  o.w = tile[4 * tx + 3][ty];
  *(float4*)(dst + (size_t)(kl0 + ty) * 4096 + io0 + 4 * tx) = o;
}

// ---------------------------------------------------------------------------
// Forward truncated DFT per (b,i) plane — MFMA version.
// Step 1: X1[l][h] = sum_w T[l][w] x[h][w]; A = twiddles (in-register
//   recurrence), B = x straight from global (8 contiguous floats/lane).
//   M=32 (re|im), N=128 (h, 2 n-tiles/wave), K=128 (4 k-steps).
// Step 2: X[k][l], K=256 (X1r|X1i stacked along h), split across 4 waves,
//   partial C reduced via LDS. Output xf_t[kl][plane] scaled 1/128.
// ---------------------------------------------------------------------------
__global__ __launch_bounds__(256) void fwd_dft_kernel(
    const float* __restrict__ x, float* __restrict__ xfr_t,
    float* __restrict__ xfi_t) {
  __shared__ unsigned short s_x1[32 * 136];  // [l | 16+l][h], bf16, pad 136
  __shared__ float s_red[8 * 256];           // 4 waves x {re,im} partial C
  const int t = threadIdx.x;
  const int plane = blockIdx.x;
  const int wv = t >> 6, lane = t & 63, l15 = lane & 15, quad = lane >> 4;

  union U8 {
    bf16x8 v;
    unsigned short u[8];
  };

  // rotation step for both stages: angle increment l15 * 2pi/128
  float dC, dS;
  sincosf(TWO_PI_128 * (float)l15, &dS, &dC);

  // ---- step 1 A-fragments (re: cos(wl), im: -sin(wl)) ----
  U8 a_re[4], a_im[4];
#pragma unroll
  for (int ks = 0; ks < 4; ++ks) {
    const int w0 = ks * 32 + quad * 8;
    float c, s;
    sincosf(TWO_PI_128 * (float)((l15 * w0) & 127), &s, &c);
#pragma unroll
    for (int j = 0; j < 8; ++j) {
      a_re[ks].u[j] = f2bf(c);
      a_im[ks].u[j] = f2bf(-s);
      float nc = c * dC - s * dS;
      s = s * dC + c * dS;
      c = nc;
    }
  }

  const float* xp = x + (size_t)plane * 16384;
  f32x4 acc[2][2];
#pragma unroll
  for (int mt = 0; mt < 2; ++mt)
#pragma unroll
    for (int nt = 0; nt < 2; ++nt) acc[mt][nt] = (f32x4){0.f, 0.f, 0.f, 0.f};

#pragma unroll
  for (int ks = 0; ks < 4; ++ks) {
#pragma unroll
    for (int nt = 0; nt < 2; ++nt) {
      const float* src =
          xp + (size_t)((wv * 2 + nt) * 16 + l15) * 128 + ks * 32 + quad * 8;
      float4 v0 = *(const float4*)src;
      float4 v1 = *(const float4*)(src + 4);
      U8 bx;
      bx.u[0] = f2bf(v0.x);
      bx.u[1] = f2bf(v0.y);
      bx.u[2] = f2bf(v0.z);
      bx.u[3] = f2bf(v0.w);
      bx.u[4] = f2bf(v1.x);
      bx.u[5] = f2bf(v1.y);
      bx.u[6] = f2bf(v1.z);
      bx.u[7] = f2bf(v1.w);
      acc[0][nt] = __builtin_amdgcn_mfma_f32_16x16x32_bf16(a_re[ks].v, bx.v,
                                                           acc[0][nt], 0, 0, 0);
      acc[1][nt] = __builtin_amdgcn_mfma_f32_16x16x32_bf16(a_im[ks].v, bx.v,
                                                           acc[1][nt], 0, 0, 0);
    }
  }

  // D[m=l (re) / 16+l (im)][n=h] -> s_x1[row][h] bf16
#pragma unroll
  for (int mt = 0; mt < 2; ++mt)
#pragma unroll
    for (int nt = 0; nt < 2; ++nt)
#pragma unroll
      for (int r = 0; r < 4; ++r)
        s_x1[(mt * 16 + quad * 4 + r) * 136 + (wv * 2 + nt) * 16 + l15] =
            f2bf(acc[mt][nt][r]);
  __syncthreads();

  // ---- step 2: Re(X) = cos.X1r + sin.X1i ; Im(X) = cos.X1i - sin.X1r ----
  f32x4 accre = (f32x4){0.f, 0.f, 0.f, 0.f};
  f32x4 accim = (f32x4){0.f, 0.f, 0.f, 0.f};
#pragma unroll
  for (int kl2 = 0; kl2 < 2; ++kl2) {
    const int ks2 = wv * 2 + kl2;            // 0..7 over K=256
    const int hb = (ks2 & 3) * 32 + quad * 8;  // h base
    const int imh = ks2 >> 2;                // 0: X1r half, 1: X1i half
    float c, s;
    sincosf(TWO_PI_128 * (float)((l15 * hb) & 127), &s, &c);
    U8 ar, ai;
#pragma unroll
    for (int j = 0; j < 8; ++j) {
      if (!imh) {
        ar.u[j] = f2bf(c);
        ai.u[j] = f2bf(-s);
      } else {
        ar.u[j] = f2bf(s);
        ai.u[j] = f2bf(c);
      }
      float nc = c * dC - s * dS;
      s = s * dC + c * dS;
      c = nc;
    }
    bf16x8 bfrag = *(const bf16x8*)(s_x1 + (imh * 16 + l15) * 136 + hb);
    accre =
        __builtin_amdgcn_mfma_f32_16x16x32_bf16(ar.v, bfrag, accre, 0, 0, 0);
    accim =
        __builtin_amdgcn_mfma_f32_16x16x32_bf16(ai.v, bfrag, accim, 0, 0, 0);
  }
  *(f32x4*)(s_red + (wv * 2) * 256 + lane * 4) = accre;
  *(f32x4*)(s_red + (wv * 2 + 1) * 256 + lane * 4) = accim;
  __syncthreads();

  const float re = s_red[t] + s_red[512 + t] + s_red[1024 + t] + s_red[1536 + t];
  const float im =
      s_red[256 + t] + s_red[768 + t] + s_red[1280 + t] + s_red[1792 + t];
  const int k = (t >> 6) * 4 + (t & 3), l = (t >> 2) & 15;
  xfr_t[(size_t)(k * 16 + l) * 1024 + plane] = re * 0.0078125f;
  xfi_t[(size_t)(k * 16 + l) * 1024 + plane] = im * 0.0078125f;
}

// ---------------------------------------------------------------------------
// Mode mix per kl (unchanged).
// ---------------------------------------------------------------------------
__global__ __launch_bounds__(256) void modemix_kernel(
    const float* __restrict__ xfr_t, const float* __restrict__ xfi_t,
    const float* __restrict__ wt_r, const float* __restrict__ wt_i,
    float* __restrict__ ofr, float* __restrict__ ofi) {
  __shared__ float s_xr[1024], s_xi[1024];  // [b][i]
  __shared__ float s_wr[4096], s_wi[4096];  // [i][o]
  const int kl = blockIdx.x;
  const int t = threadIdx.x;
  ((float4*)s_xr)[t] = ((const float4*)(xfr_t + (size_t)kl * 1024))[t];
  ((float4*)s_xi)[t] = ((const float4*)(xfi_t + (size_t)kl * 1024))[t];
  const float4* wrp = (const float4*)(wt_r + (size_t)kl * 4096);
  const float4* wip = (const float4*)(wt_i + (size_t)kl * 4096);
#pragma unroll
  for (int j = 0; j < 4; ++j) {
    ((float4*)s_wr)[t + 256 * j] = wrp[t + 256 * j];
    ((float4*)s_wi)[t + 256 * j] = wip[t + 256 * j];
  }
  __syncthreads();
  const int b0 = t >> 6;
  const int o = t & 63;
  float accr[4] = {0.f, 0.f, 0.f, 0.f};
  float acci[4] = {0.f, 0.f, 0.f, 0.f};
  for (int i = 0; i < 64; ++i) {
    float wrv = s_wr[i * 64 + o], wiv = s_wi[i * 64 + o];
#pragma unroll
    for (int j = 0; j < 4; ++j) {
      int b = b0 + 4 * j;
      float xr = s_xr[b * 64 + i], xi = s_xi[b * 64 + i];
      accr[j] = fmaf(xr, wrv, accr[j]);
      accr[j] = fmaf(-xi, wiv, accr[j]);
      acci[j] = fmaf(xr, wiv, acci[j]);
      acci[j] = fmaf(xi, wrv, acci[j]);
    }
  }
#pragma unroll
  for (int j = 0; j < 4; ++j) {
    int b = b0 + 4 * j;
    ofr[(size_t)(b * 64 + o) * 256 + kl] = accr[j];
    ofi[(size_t)(b * 64 + o) * 256 + kl] = acci[j];
  }
}

// ---------------------------------------------------------------------------
// Inverse along h. Output: packed bf16 Y[b][h][o][kk], kk=0..15 Yr, 16..31 Yi
// (64 B per (b,h,o) row) — exactly final_kernel's A-fragment staging layout.
// ---------------------------------------------------------------------------
__global__ __launch_bounds__(256) void invh_kernel(
    const float* __restrict__ ofr, const float* __restrict__ ofi,
    uint4* __restrict__ Ybf) {
  __shared__ float s_fr[16 * 260], s_fi[16 * 260];
  __shared__ float2 s_tw[128];
  const int t = threadIdx.x;
  const int bid = blockIdx.x;
  const int b = bid >> 5, og = (bid >> 3) & 3, hg = bid & 7;
  if (t < 128) {
    float sv, cv;
    sincosf(TWO_PI_128 * (float)t, &sv, &cv);
    s_tw[t] = make_float2(cv, sv);
  }
#pragma unroll 4
  for (int pp = 0; pp < 16; ++pp) {
    s_fr[pp * 260 + t] = ofr[(size_t)(b * 64 + og * 16 + pp) * 256 + t];
    s_fi[pp * 260 + t] = ofi[(size_t)(b * 64 + og * 16 + pp) * 256 + t];
  }
  __syncthreads();
  const int ol = t & 15, hl = t >> 4;
  const int h = hg * 16 + hl;
  float yr[16], yi[16];
#pragma unroll
  for (int l = 0; l < 16; ++l) {
    yr[l] = 0.f;
    yi[l] = 0.f;
  }
  const float* FR = s_fr + ol * 260;
  const float* FI = s_fi + ol * 260;
  const float2 tw = s_tw[h];
  float ck = 1.f, sk = 0.f;
#pragma unroll 4
  for (int k = 0; k < 16; ++k) {
#pragma unroll
    for (int q = 0; q < 4; ++q) {
      float4 fr = *(const float4*)(FR + k * 16 + 4 * q);
      float4 fi = *(const float4*)(FI + k * 16 + 4 * q);
      int l = 4 * q;
      yr[l + 0] = fmaf(fr.x, ck, yr[l + 0]);
      yr[l + 0] = fmaf(-fi.x, sk, yr[l + 0]);
      yi[l + 0] = fmaf(fi.x, ck, yi[l + 0]);
      yi[l + 0] = fmaf(fr.x, sk, yi[l + 0]);
      yr[l + 1] = fmaf(fr.y, ck, yr[l + 1]);
      yr[l + 1] = fmaf(-fi.y, sk, yr[l + 1]);
      yi[l + 1] = fmaf(fi.y, ck, yi[l + 1]);
      yi[l + 1] = fmaf(fr.y, sk, yi[l + 1]);
      yr[l + 2] = fmaf(fr.z, ck, yr[l + 2]);
      yr[l + 2] = fmaf(-fi.z, sk, yr[l + 2]);
      yi[l + 2] = fmaf(fi.z, ck, yi[l + 2]);
      yi[l + 2] = fmaf(fr.z, sk, yi[l + 2]);
      yr[l + 3] = fmaf(fr.w, ck, yr[l + 3]);
      yr[l + 3] = fmaf(-fi.w, sk, yr[l + 3]);
      yi[l + 3] = fmaf(fi.w, ck, yi[l + 3]);
      yi[l + 3] = fmaf(fr.w, sk, yi[l + 3]);
    }
    float tt = sk * tw.y, uu = ck * tw.y;
    ck = fmaf(ck, tw.x, -tt);
    sk = fmaf(sk, tw.x, uu);
  }
  unsigned int u[16];
  {
    float sc[16];
    sc[0] = 0.0078125f;
#pragma unroll
    for (int l = 1; l < 16; ++l) sc[l] = 0.015625f;
#pragma unroll
    for (int j = 0; j < 8; ++j) {
      u[j] = (unsigned)f2bf(yr[2 * j] * sc[2 * j]) |
             ((unsigned)f2bf(yr[2 * j + 1] * sc[2 * j + 1]) << 16);
      u[8 + j] = (unsigned)f2bf(yi[2 * j] * sc[2 * j]) |
                 ((unsigned)f2bf(yi[2 * j + 1] * sc[2 * j + 1]) << 16);
    }
  }
  uint4* dst = Ybf + ((size_t)(b * 128 + h) * 64 + og * 16 + ol) * 4;
  dst[0] = make_uint4(u[0], u[1], u[2], u[3]);
  dst[1] = make_uint4(u[4], u[5], u[6], u[7]);
  dst[2] = make_uint4(u[8], u[9], u[10], u[11]);
  dst[3] = make_uint4(u[12], u[13], u[14], u[15]);
}

// ---------------------------------------------------------------------------
// Final fused, MFMA (unchanged from R3).
// ---------------------------------------------------------------------------
__global__ __launch_bounds__(256) void final_kernel(
    const float* __restrict__ x, const float* __restrict__ bw,
    const float* __restrict__ bb, const float* __restrict__ proj,
    const uint4* __restrict__ Ybf, float* __restrict__ out) {
#define AR 104
  __shared__ unsigned short s_A[64 * AR];
  __shared__ float s_bb[64];
  __shared__ float s_pb[64];
  const int h = blockIdx.x, b = blockIdx.y, t = threadIdx.x;

  if (t < 64)
    s_bb[t] = bb[t];
  else if (t < 128)
    s_pb[t - 64] = proj[b * 64 + (t - 64)];

  {
    const int o = t >> 2, q = t & 3;
    const float4* src = (const float4*)(bw + o * 64 + q * 16);
    unsigned int u[8];
#pragma unroll
    for (int m = 0; m < 4; ++m) {
      float4 v = src[m];
      u[2 * m] = (unsigned)f2bf(v.x) | ((unsigned)f2bf(v.y) << 16);
      u[2 * m + 1] = (unsigned)f2bf(v.z) | ((unsigned)f2bf(v.w) << 16);
    }
    uint4* dst = (uint4*)(s_A + o * AR + q * 16);
    dst[0] = make_uint4(u[0], u[1], u[2], u[3]);
    dst[1] = make_uint4(u[4], u[5], u[6], u[7]);
  }
  {
    const int o = t >> 2, q = t & 3;
    uint4 v = Ybf[((size_t)(b * 128 + h) * 64 + o) * 4 + q];
    *(uint4*)(s_A + o * AR + 64 + q * 8) = v;
  }
  __syncthreads();

  const int wv = t >> 6, lane = t & 63;
  const int l15 = lane & 15, quad = lane >> 4;
  const int n0w = wv * 32;

  f32x4 acc[4][2];
#pragma unroll
  for (int mt = 0; mt < 4; ++mt) {
    f32x4 bv = *(const f32x4*)(s_bb + mt * 16 + quad * 4);
    acc[mt][0] = bv;
    acc[mt][1] = bv;
  }

  const float* xrow = x + (size_t)b * 1048576 + (size_t)h * 128 + n0w + l15;
#pragma unroll
  for (int ks = 0; ks < 64; ks += 32) {
    union {
      bf16x8 v;
      unsigned short u[8];
    } bx[2];
#pragma unroll
    for (int nt = 0; nt < 2; ++nt) {
      float xv[8];
#pragma unroll
      for (int j = 0; j < 8; ++j)
        xv[j] = xrow[(size_t)(ks + quad * 8 + j) * 16384 + nt * 16];
#pragma unroll
      for (int j = 0; j < 8; ++j) bx[nt].u[j] = f2bf(xv[j]);
    }
#pragma unroll
    for (int mt = 0; mt < 4; ++mt) {
      bf16x8 a = *(const bf16x8*)(s_A + (mt * 16 + l15) * AR + ks + quad * 8);
      acc[mt][0] = __builtin_amdgcn_mfma_f32_16x16x32_bf16(a, bx[0].v,
                                                           acc[mt][0], 0, 0, 0);
      acc[mt][1] = __builtin_amdgcn_mfma_f32_16x16x32_bf16(a, bx[1].v,
                                                           acc[mt][1], 0, 0, 0);
    }
  }

  {
    const int lbase = (quad & 1) * 8;
    const bool iscos = (quad < 2);
    union {
      bf16x8 v;
      unsigned short u[8];
    } bs[2];
#pragma unroll
    for (int nt = 0; nt < 2; ++nt) {
      const int wn = n0w + nt * 16 + l15;
      float st, ct, ss, cc;
      sincosf(TWO_PI_128 * (float)wn, &st, &ct);
      sincosf(TWO_PI_128 * (float)(wn * lbase), &ss, &cc);
#pragma unroll
      for (int j = 0; j < 8; ++j) {
        bs[nt].u[j] = f2bf(iscos ? cc : -ss);
        float nc = cc * ct - ss * st;
        ss = ss * ct + cc * st;
        cc = nc;
      }
    }
#pragma unroll
    for (int mt = 0; mt < 4; ++mt) {
      bf16x8 a = *(const bf16x8*)(s_A + (mt * 16 + l15) * AR + 64 + quad * 8);
      acc[mt][0] = __builtin_amdgcn_mfma_f32_16x16x32_bf16(a, bs[0].v,
                                                           acc[mt][0], 0, 0, 0);
      acc[mt][1] = __builtin_amdgcn_mfma_f32_16x16x32_bf16(a, bs[1].v,
                                                           acc[mt][1], 0, 0, 0);
    }
  }

#pragma unroll
  for (int mt = 0; mt < 4; ++mt) {
    f32x4 pv = *(const f32x4*)(s_pb + mt * 16 + quad * 4);
#pragma unroll
    for (int nt = 0; nt < 2; ++nt) {
      const int wcol = n0w + nt * 16 + l15;
#pragma unroll
      for (int r = 0; r < 4; ++r) {
        const int o = mt * 16 + quad * 4 + r;
        float v = acc[mt][nt][r];
        float g = fmaf(0.5f * v, 1.f + erff(v * 0.70710678f), pv[r]);
        out[((size_t)(b * 64 + o) * 128 + h) * 128 + wcol] = g;
      }
    }
  }
#undef AR
}

// ---------------------------------------------------------------------------
extern "C" void kernel_launch(void* const* d_in, const int* in_sizes, int n_in,
                              void* d_out, int out_size, void* d_ws,
                              size_t ws_size, hipStream_t stream) {
  (void)in_sizes;
  (void)n_in;
  (void)out_size;
  (void)ws_size;
  const float* x = (const float*)d_in[0];
  const float* t_emb = (const float*)d_in[1];
  const float* wr = (const float*)d_in[2];
  const float* wi = (const float*)d_in[3];
  const float* bw = (const float*)d_in[4];
  const float* bb = (const float*)d_in[5];
  const float* tw = (const float*)d_in[6];
  const float* tb = (const float*)d_in[7];
  float* out = (float*)d_out;

  char* ws = (char*)d_ws;
  float* proj = (float*)(ws);
  float* ofr = (float*)(ws + ((size_t)1 << 20));
  float* ofi = (float*)(ws + ((size_t)2 << 20));
  float* xfr_t = (float*)(ws + ((size_t)3 << 20));
  float* xfi_t = (float*)(ws + ((size_t)4 << 20));
  float* wt_r = (float*)(ws + ((size_t)5 << 20));
  float* wt_i = (float*)(ws + ((size_t)9 << 20));
  uint4* Ybf = (uint4*)(ws + ((size_t)3 << 20));

  proj_kernel<<<16, 256, 0, stream>>>(t_emb, tw, tb, proj);
  wtrans_kernel<<<dim3(8, 128, 2), 256, 0, stream>>>(wr, wi, wt_r, wt_i);
  fwd_dft_kernel<<<1024, 256, 0, stream>>>(x, xfr_t, xfi_t);
  modemix_kernel<<<256, 256, 0, stream>>>(xfr_t, xfi_t, wt_r, wt_i, ofr, ofi);
  invh_kernel<<<512, 256, 0, stream>>>(ofr, ofi, Ybf);
  final_kernel<<<dim3(128, 16), 256, 0, stream>>>(x, bw, bb, proj, Ybf, out);
}